// Round 10
// baseline (364.852 us; speedup 1.0000x reference)
//
#include <hip/hip_runtime.h>
#include <hip/hip_bf16.h>
#include <math.h>

#define NSUB 16
#define NLAB 8
#define KG 128
#define BN 16384
#define DD 1024

typedef float v4f __attribute__((ext_vector_type(4)));
typedef short short8v __attribute__((ext_vector_type(8)));
typedef unsigned short ushort4v __attribute__((ext_vector_type(4)));

static __device__ __forceinline__ short f2bf(float f) {
    unsigned u = __builtin_bit_cast(unsigned, f);
    unsigned r = (u + 0x7fffu + ((u >> 16) & 1u)) >> 16;   // RNE
    return (short)r;
}

static __device__ __forceinline__ float bf2f(unsigned short u) {
    unsigned v = ((unsigned)u) << 16;
    return __builtin_bit_cast(float, v);
}

static __device__ __forceinline__ unsigned packbf2(float x, float y) {
    union { __hip_bfloat162 h; unsigned u; } c;
    c.h = __float22bfloat162_rn(float2{x, y});
    return c.u;
}

// K0: gid + per-block group histogram; block 0 also zeroes sqsG for k5a's atomics.
__global__ __launch_bounds__(1024) void k0_gid(const int* __restrict__ subject,
                                               const int* __restrict__ labels,
                                               int* __restrict__ gid, int* __restrict__ hist,
                                               float* __restrict__ sqsG) {
    __shared__ int h[KG];
    int t = threadIdx.x;
    if (t < KG) h[t] = 0;
    if (blockIdx.x == 0 && t < KG) sqsG[t] = 0.f;
    __syncthreads();
    int b = blockIdx.x * 1024 + t;
    int g = subject[b] * NLAB + labels[b];
    gid[b] = g;
    atomicAdd(&h[g], 1);
    __syncthreads();
    if (t < KG) hist[blockIdx.x * KG + t] = h[t];
}

// FR: the single fused X pass. Grid = 32 row-chunks x 32 d-chunks; block = 1024 feat-rows
// x 32 d. Per element: (a) bf16 -> Atil fragment store (8 B pieces, dense within the
// block's tile regions -> L2 write-combines), (b) LDS atomicAdd into padded group bins.
// 16 B/lane coalesced X loads (the r7 scatter kernel's fatal flaw was 4 B/lane).
// Atil ushort idx = rt*16384 + kc*512 + q*128 + m*8 + jj, k = kc*32 + q*8 + jj (kc = dc).
__global__ __launch_bounds__(256) void fr_stream(const float* __restrict__ X,
                                                 const int* __restrict__ gid,
                                                 unsigned short* __restrict__ Atil,
                                                 float* __restrict__ part) {
    __shared__ float acc[KG * 33];      // +1-word pad per group row: breaks bank alias
    __shared__ int rg[1024];
    int t = threadIdx.x;
    int rc = blockIdx.x >> 5, dc = blockIdx.x & 31;
    for (int i = t; i < KG * 33; i += 256) acc[i] = 0.f;
    int rbase = rc * 1024;
    for (int i = t; i < 1024; i += 256) rg[i] = gid[(rbase + i) & (BN - 1)];
    __syncthreads();
    int rsub = t >> 3;                  // 0..31: row-in-iteration
    int dsl = (t & 7) * 4;              // 0,4,...,28: d-offset within the 32-d slice
    int d0 = dc * 32 + dsl;
    int q = (dsl >> 3) & 3, jj = dsl & 7;
#pragma unroll 2
    for (int it = 0; it < 32; ++it) {
        int ri = it * 32 + rsub;        // row-in-block 0..1023
        int rglob = rbase + ri;
        const float* xp = X + (size_t)(rglob & (BN - 1)) * 2048 +
                          (size_t)(rglob >> 14) * 1024 + d0;
        float4 v = *(const float4*)xp;
        int g = rg[ri];
        // Atil fragment store (bf16)
        int rt = rglob >> 4, m = rglob & 15;
        ushort4 sv;
        sv.x = (unsigned short)f2bf(v.x); sv.y = (unsigned short)f2bf(v.y);
        sv.z = (unsigned short)f2bf(v.z); sv.w = (unsigned short)f2bf(v.w);
        *(ushort4*)(Atil + (size_t)rt * 16384 + dc * 512 + q * 128 + m * 8 + jj) = sv;
        // centroid scatter into LDS bins
        float* ap = &acc[g * 33 + dsl];
        atomicAdd(ap, v.x); atomicAdd(ap + 1, v.y);
        atomicAdd(ap + 2, v.z); atomicAdd(ap + 3, v.w);
    }
    __syncthreads();
    // dump bins: part[(rc*KG + g)*1024 + dc*32 + dloc]
    for (int idx = t; idx < KG * 32; idx += 256) {
        int g = idx >> 5, dloc = idx & 31;
        part[((size_t)rc * KG + g) * 1024 + dc * 32 + dloc] = acc[g * 33 + dloc];
    }
}

// K1r2: reduce the 32 row-chunk partials per (g,d) -> centroid; frag-tiled Btil + cnorm.
// Also derives cnt[g] from hist (the counting sort is gone). No 512-row cap anymore.
__global__ __launch_bounds__(256) void k1r2_reduce(const float* __restrict__ part,
                                                   const int* __restrict__ hist,
                                                   unsigned short* __restrict__ Btil,
                                                   float* __restrict__ cnormPart,
                                                   int* __restrict__ cnt) {
    int g = blockIdx.x, t = threadIdx.x, lane = t & 63, w = t >> 6;
    __shared__ float wsum[4];
    __shared__ int n_sh;
    if (t == 0) {
        int n = 0;
        for (int j = 0; j < 16; ++j) n += hist[j * KG + g];
        cnt[g] = n;
        n_sh = n;
    }
    __syncthreads();
    int d0 = t * 4;
    const float* pp = part + (size_t)g * 1024 + d0;
    float4 s4 = make_float4(0.f, 0.f, 0.f, 0.f);
    for (int rc = 0; rc < 32; ++rc) {
        float4 v = *(const float4*)(pp + (size_t)rc * KG * 1024);
        s4.x += v.x; s4.y += v.y; s4.z += v.z; s4.w += v.w;
    }
    float inv = 1.f / (2.f * (float)n_sh);
    float cx[4] = {s4.x * inv, s4.y * inv, s4.z * inv, s4.w * inv};
    int base_t = (d0 >> 5) * 512 + ((d0 >> 3) & 3) * 128 + (g & 15) * 8 + (d0 & 7);
    uint2 st;
    st.x = packbf2(cx[0], cx[1]);
    st.y = packbf2(cx[2], cx[3]);
    *(uint2*)(Btil + (size_t)(g >> 4) * 16384 + base_t) = st;
    float s = cx[0] * cx[0] + cx[1] * cx[1] + cx[2] * cx[2] + cx[3] * cx[3];
#pragma unroll
    for (int x = 32; x; x >>= 1) s += __shfl_xor(s, x, 64);
    if (lane == 0) wsum[w] = s;
    __syncthreads();
    if (t == 0) {
        cnormPart[g] = wsum[0] + wsum[1] + wsum[2] + wsum[3];
        cnormPart[KG + g] = 0.f;
    }
}

// K5a: bf16 MFMA GEMM with LDS-staged double-buffered B; group sqrt-dist sums go
// straight to global sqsG[128] via atomicAdd. (Byte-identical to the passing r9 version.)
__global__ __launch_bounds__(256) void k5a_dot(const unsigned short* __restrict__ Atil,
                                               const unsigned short* __restrict__ Btil,
                                               const int* __restrict__ gid,
                                               const float* __restrict__ cnormPart,
                                               unsigned short* __restrict__ Dotb,
                                               float* __restrict__ sqsG) {
    __shared__ float h[KG];
    __shared__ float cnormS[KG];
    __shared__ uint4 Bs[2][512];    // 2 x 8 KB B-chunk double buffer
    int t = threadIdx.x, lane = t & 63, w = t >> 6;
    if (t < KG) {
        h[t] = 0.f;
        cnormS[t] = cnormPart[t] + cnormPart[KG + t];
    }
    int rt = blockIdx.x * 4 + w;            // 16-row tile
    int m = lane & 15, q = lane >> 4;
    const unsigned short* ap = Atil + (size_t)rt * 16384 + lane * 8;
    int sgt = t >> 5, so = t & 31;          // staging role: gt 0..7, 2 x uint4 each
    const unsigned short* bgp = Btil + (size_t)sgt * 16384;

    {   // stage kc = 0
        const uint4* gp = (const uint4*)bgp;
        Bs[0][sgt * 64 + so] = gp[so];
        Bs[0][sgt * 64 + so + 32] = gp[so + 32];
    }
    v4f acc[8];
#pragma unroll
    for (int j = 0; j < 8; ++j) acc[j] = (v4f){0.f, 0.f, 0.f, 0.f};
    short8v afc = *(const short8v*)ap;
    __syncthreads();                         // Bs[0] + h/cnormS ready

    float s0 = 0.f;
#pragma unroll
    for (int kc = 0; kc < 32; ++kc) {
        const int cur = kc & 1;
        if (kc + 1 < 32) {                   // stage next chunk into the other buffer
            const uint4* gp = (const uint4*)(bgp + (kc + 1) * 512);
            Bs[cur ^ 1][sgt * 64 + so] = gp[so];
            Bs[cur ^ 1][sgt * 64 + so + 32] = gp[so + 32];
        }
        short8v afn;
        if (kc + 1 < 32) afn = *(const short8v*)(ap + (kc + 1) * 512);
        const short8v* bsv = (const short8v*)Bs[cur];
#pragma unroll
        for (int gt = 0; gt < 8; ++gt)
            acc[gt] = __builtin_amdgcn_mfma_f32_16x16x32_bf16(afc, bsv[gt * 64 + lane], acc[gt], 0, 0, 0);
        {
            union { short8v s; unsigned u[4]; } ua;
            ua.s = afc;
#pragma unroll
            for (int r = 0; r < 4; ++r) {
                float l0 = __builtin_bit_cast(float, ua.u[r] << 16);
                float h0 = __builtin_bit_cast(float, ua.u[r] & 0xffff0000u);
                s0 = fmaf(l0, l0, s0); s0 = fmaf(h0, h0, s0);
            }
        }
        if (kc + 1 < 32) afc = afn;
        __syncthreads();                     // writes visible; all reads of Bs[cur] done
    }

    // s0 = ||rt*16 + (lane&15)||^2 on all lanes after q-reduction
    s0 += __shfl_xor(s0, 16, 64); s0 += __shfl_xor(s0, 32, 64);

    int bid = blockIdx.x;
#pragma unroll
    for (int reg = 0; reg < 4; ++reg) {
        int rr = w * 16 + q * 4 + reg;
        int row = bid * 64 + rr;
        int b = row & (BN - 1);
        int g = gid[b];
        float own = 0.f;
#pragma unroll
        for (int gt = 0; gt < 8; ++gt) {
            float v = acc[gt][reg];
            size_t idx = (((size_t)bid * 32 + gt * 4 + (m >> 2)) * 64 + rr) * 4 + (m & 3);
            Dotb[idx] = (unsigned short)f2bf(v);
            if ((g >> 4) == gt) own = v;
        }
        float rn = __shfl(s0, q * 4 + reg, 64);
        if ((g & 15) == m) {
            float d2 = fmaxf(rn - 2.f * own + cnormS[g], 0.f);
            atomicAdd(&h[g], sqrtf(sqrtf(d2)));   // sqrt(dist), dist = sqrt(d2)
        }
    }
    __syncthreads();
    if (t < KG) atomicAdd(&sqsG[t], h[t]);
}

// K5b: density post-processing + loss. sqsG is the already-reduced 128-float sum.
// (Byte-identical to the passing r9 version.)
__global__ __launch_bounds__(128) void k5b_loss(const unsigned short* __restrict__ Dotb,
                                                const int* __restrict__ gid,
                                                const float* __restrict__ sqsG,
                                                const int* __restrict__ cnt,
                                                float* __restrict__ out) {
    __shared__ float tmp[KG], d1s[KG], qv[4];
    __shared__ float recipDen[KG];
    __shared__ float wsum[2];
    int t = threadIdx.x;
    // ---- density (all 128 threads; barriers uniform) ----
    float cntf = 0.f, d0v = 0.f, v = 0.f;
    if (t < KG) {
        float ss = sqsG[t];
        cntf = 2.f * (float)cnt[t];
        d0v = (ss / cntf) / logf(cntf + 10.f);
        tmp[t] = d0v;
    }
    __syncthreads();
    if (t < KG) {
        float dmax = -INFINITY;
        for (int j = 0; j < KG; ++j) dmax = fmaxf(dmax, tmp[j]);
        v = (cntf <= 1.f) ? dmax : d0v;
        d1s[t] = v;
    }
    __syncthreads();
    if (t < KG) {
        int less = 0, eq = 0;
        for (int j = 0; j < KG; ++j) {
            float u = d1s[j];
            less += (u < v) ? 1 : 0;
            eq += (u == v) ? 1 : 0;
        }
        // quantile(0.1): idx 12.7 -> 0.3*v[12]+0.7*v[13]; quantile(0.9): 0.7*v[114]+0.3*v[115]
        const int ppos[4] = {12, 13, 114, 115};
        for (int qq = 0; qq < 4; ++qq)
            if (less <= ppos[qq] && ppos[qq] < less + eq) qv[qq] = v;
    }
    __syncthreads();
    if (t < KG) {
        float q10 = 0.3f * qv[0] + 0.7f * qv[1];
        float q90 = 0.7f * qv[2] + 0.3f * qv[3];
        tmp[t] = fminf(fmaxf(v, q10), q90);
    }
    __syncthreads();
    if (t < KG) {
        float sum = 0.f;
        for (int j = 0; j < KG; ++j) sum += tmp[j];
        float mean = sum / (float)KG;
        recipDen[t] = mean / (0.1f * tmp[t]);   // 1/den
    }
    __syncthreads();
    // ---- loss: one thread per row ----
    int row = blockIdx.x * 128 + t;
    int b = row & (BN - 1);
    int g = gid[b];
    int s = g >> 3, l = g & 7;
    int lane = t & 63, w = t >> 6;
    size_t rowblk = (size_t)(row >> 6);
    const ushort4v* dp = (const ushort4v*)Dotb;
    float mx = -INFINITY;
    float psave[16];
#pragma unroll
    for (int c = 0; c < 16; ++c) {
        size_t i0 = (rowblk * 32 + c * 2) * 64 + lane;
        ushort4v dv0 = dp[i0];
        ushort4v dv1 = dp[i0 + 64];
        const float* rv = &recipDen[c * 8];
        float x[8];
#pragma unroll
        for (int j = 0; j < 4; ++j) x[j] = bf2f((unsigned short)dv0[j]) * rv[j];
#pragma unroll
        for (int j = 0; j < 4; ++j) x[4 + j] = bf2f((unsigned short)dv1[j]) * rv[4 + j];
#pragma unroll
        for (int j = 0; j < 8; ++j) mx = fmaxf(mx, x[j]);
        float sel = x[0];
#pragma unroll
        for (int j = 1; j < 8; ++j) sel = (j == l) ? x[j] : sel;
        psave[c] = sel;
    }
    float S = 0.f, P = 0.f;
#pragma unroll
    for (int j = 0; j < 16; ++j) {
        float pv = psave[j] - mx;
        float e = expf(pv);
        bool use = (j != s);
        S += use ? e : 0.f;
        P += use ? pv : 0.f;
    }
    // 113 masked-out entries contribute exp(0)=1 each to the softmax denominator
    float ll = logf(113.f + S) - P * (1.f / 15.f);
#pragma unroll
    for (int x2 = 32; x2; x2 >>= 1) ll += __shfl_xor(ll, x2, 64);
    if (lane == 0) wsum[w] = ll;
    __syncthreads();
    if (t == 0) atomicAdd(out, (wsum[0] + wsum[1]) * (1.f / 32768.f));
}

extern "C" void kernel_launch(void* const* d_in, const int* in_sizes, int n_in,
                              void* d_out, int out_size, void* d_ws, size_t ws_size,
                              hipStream_t stream) {
    const float* X = (const float*)d_in[0];
    const int* subject = (const int*)d_in[1];
    const int* labels = (const int*)d_in[2];
    float* out = (float*)d_out;
    char* w = (char*)d_ws;
    int* gid = (int*)(w + 0);                              // 64 KB
    int* hist = (int*)(w + 65536);                         // 8 KB  (16 x 128)
    int* cnt = (int*)(w + 73728);                          // 512 B
    float* cnormPart = (float*)(w + 74240);                // 1 KB  (2 x 128)
    float* sqsG = (float*)(w + 262144);                    // 512 B (128 floats)
    unsigned short* Btil = (unsigned short*)(w + 524288);  // 256 KB (frag-tiled centroids)
    unsigned short* Atil = (unsigned short*)(w + 2097152); // 64 MB  (frag-tiled bf16 X)
    float* part = (float*)(w + 71303168);                  // 16 MB (32 x 128 x 1024 fp32)
    unsigned short* Dotb = (unsigned short*)(w + 100663296); // 8 MB (tiled bf16 Dot)

    (void)hipMemsetAsync(out, 0, sizeof(float), stream);

    k0_gid<<<16, 1024, 0, stream>>>(subject, labels, gid, hist, sqsG);
    fr_stream<<<1024, 256, 0, stream>>>(X, gid, Atil, part);
    k1r2_reduce<<<KG, 256, 0, stream>>>(part, hist, Btil, cnormPart, cnt);
    k5a_dot<<<512, 256, 0, stream>>>(Atil, Btil, gid, cnormPart, Dotb, sqsG);
    k5b_loss<<<256, 128, 0, stream>>>(Dotb, gid, sqsG, cnt, out);
}